// Round 7
// baseline (598.810 us; speedup 1.0000x reference)
//
#include <hip/hip_runtime.h>

// GCN forward on MI355X — bf16 intermediate pipeline.
//
// R11: spmm1_fused was measured VALU-bound (130us, VALUBusy 66%, MfmaUtil 0,
// HBM 35%). Move descriptor handling to the SCALAR pipe: edge descriptors
// loaded at wave-uniform addresses (s_load, zero VALU) instead of vector
// load + 2 readlanes/edge; gathers become saddr-form with SGPR col; FMA
// takes val as SGPR operand. Matvec: readlane->SGPR, extraction via SALU
// (s_lshl/s_and free), W2 pre-paired in LDS (ds_read_b64), all lanes
// compute full k-sum (no shfl combine). spmm2: same scalar-descriptor
// treatment with a cndmask select-tree per 4-edge group.

#define NN 100000
#define NE 3200000
#define FIN 512
#define FHID 128
#define FOUT 32
#define BROWS 64             // rows per bucket
#define NBUCK 1563           // ceil(NN/64)
#define NPART 256            // scatter partitions
#define CHUNK 12500          // edges per partition; NPART*CHUNK == NE exactly
#define TOT (NBUCK * NPART)  // 400128 counter cells
#define NSCAN1 391           // ceil(TOT/1024)
#define EBCAP 2560           // bucket LDS staging capacity (E[n]=2048)
#define EPT 25               // edges per thread in scatter (ceil(12500/512))
#define GG1 ((NN + 127) / 128)  // gemm1 blocks = 782

typedef __attribute__((ext_vector_type(8))) short bf16x8;
typedef __attribute__((ext_vector_type(4))) float f32x4;

static __device__ __forceinline__ unsigned short f2bf(float f) {
    unsigned u = __float_as_uint(f);
    unsigned r = (u + 0x7FFFu + ((u >> 16) & 1u)) >> 16;  // RTN-even
    return (unsigned short)r;
}
static __device__ __forceinline__ float bf2f(unsigned short u) {
    return __uint_as_float(((unsigned)u) << 16);
}
static __device__ __forceinline__ float bflo(unsigned u) {
    return __uint_as_float(u << 16);
}
static __device__ __forceinline__ float bfhi(unsigned u) {
    return __uint_as_float(u & 0xffff0000u);
}
static __device__ __forceinline__ bf16x8 pack8(float4 u, float4 v) {
    bf16x8 r;
    r[0] = (short)f2bf(u.x); r[1] = (short)f2bf(u.y);
    r[2] = (short)f2bf(u.z); r[3] = (short)f2bf(u.w);
    r[4] = (short)f2bf(v.x); r[5] = (short)f2bf(v.y);
    r[6] = (short)f2bf(v.z); r[7] = (short)f2bf(v.w);
    return r;
}

// ---------------- CSR build phase 1: hist (+ fused W1 fragment-shuffle) ----------------
__global__ __launch_bounds__(256) void fused_prep_hist(const float* __restrict__ W1,
                                                       unsigned short* __restrict__ W1t,
                                                       const int* __restrict__ erow,
                                                       int* __restrict__ cntG) {
    if (blockIdx.x < NPART) {
        __shared__ int c[NBUCK];
        const int t = threadIdx.x;
        const int w = blockIdx.x;
        for (int i = t; i < NBUCK; i += 256) c[i] = 0;
        __syncthreads();
        const int e0 = w * CHUNK;
        const int e1 = min(e0 + CHUNK, NE);
        for (int e = e0 + t; e < e1; e += 256) atomicAdd(&c[erow[e] >> 6], 1);
        __syncthreads();
        for (int i = t; i < NBUCK; i += 256) cntG[w * NBUCK + i] = c[i];
    } else {
        int t = (blockIdx.x - NPART) * 256 + threadIdx.x;  // 65536 threads
        int j = t & 7;
        int c = t >> 3;
        int l = c & 63;
        int ks = (c >> 6) & 15;
        int nt = c >> 10;
        int n = nt * 16 + (l & 15);
        int k = ks * 32 + ((l >> 4) << 3) + j;
        W1t[(size_t)c * 8 + j] = f2bf(W1[k * FHID + n]);
    }
}

__global__ __launch_bounds__(256) void scan1_kernel(const int* __restrict__ cntG,
                                                    int* __restrict__ off,
                                                    int* __restrict__ partials) {
    __shared__ int s[256];
    int t = threadIdx.x;
    int i0 = blockIdx.x * 1024 + t * 4;
    int v[4];
#pragma unroll
    for (int j = 0; j < 4; ++j) {
        int i = i0 + j;
        // flat index i = b*NPART + w (bucket-major); cntG is [w][b]
        v[j] = (i < TOT) ? cntG[(i & (NPART - 1)) * NBUCK + (i >> 8)] : 0;
    }
    int lsum = v[0] + v[1] + v[2] + v[3];
    s[t] = lsum;
    __syncthreads();
    for (int o = 1; o < 256; o <<= 1) {
        int xv = (t >= o) ? s[t - o] : 0;
        __syncthreads();
        s[t] += xv;
        __syncthreads();
    }
    if (t == 255) partials[blockIdx.x] = s[255];
    int run = s[t] - lsum;
#pragma unroll
    for (int j = 0; j < 4; ++j) {
        if (i0 + j < TOT) off[i0 + j] = run;
        run += v[j];
    }
}

__global__ __launch_bounds__(512) void scan2_kernel(int* partials) {
    __shared__ int s[512];
    int t = threadIdx.x;
    int v = (t < NSCAN1) ? partials[t] : 0;
    s[t] = v;
    __syncthreads();
    for (int o = 1; o < 512; o <<= 1) {
        int xv = (t >= o) ? s[t - o] : 0;
        __syncthreads();
        s[t] += xv;
        __syncthreads();
    }
    if (t < NSCAN1) partials[t] = s[t] - v;
}

// ---------------- scatter_part: LDS-staged radix scatter ----------------
__global__ __launch_bounds__(512) void scatter_part(const int* __restrict__ erow,
                                                    const int* __restrict__ ecol,
                                                    const float* __restrict__ eval,
                                                    const int* __restrict__ off,
                                                    const int* __restrict__ partials,
                                                    int2* __restrict__ bcolval) {
    __shared__ int2 eb2[CHUNK];            // 100000 B
    __shared__ unsigned short bkt2[CHUNK]; // 25000 B
    __shared__ int cnt[NBUCK];             // raw counts -> exclusive offsets
    __shared__ int pos[NBUCK];             // running cursors
    __shared__ int ofsG[NBUCK];            // final global base per bucket
    __shared__ int s[512];                 // block-scan workspace
    const int t = threadIdx.x;
    const int w = blockIdx.x;
    const int e0 = w * CHUNK;

    for (int i = t; i < NBUCK; i += 512) cnt[i] = 0;
    __syncthreads();

    // --- A: load + count ---
    int myb[EPT];
    int2 myrec[EPT];
#pragma unroll
    for (int ii = 0; ii < EPT; ++ii) {
        int i = t + ii * 512;
        myb[ii] = -1;
        if (i < CHUNK) {
            int e = e0 + i;
            int r = erow[e];
            int b = r >> 6;
            myb[ii] = b;
            myrec[ii] = make_int2(ecol[e] | ((r & 63) << 20), __float_as_int(eval[e]));
            atomicAdd(&cnt[b], 1);
        }
    }
    __syncthreads();

    // --- B: exclusive scan of cnt[0..NBUCK) in place ---
    int base = t * 4;
    int v[4];
#pragma unroll
    for (int j = 0; j < 4; ++j) v[j] = (base + j < NBUCK) ? cnt[base + j] : 0;
    int lsum = v[0] + v[1] + v[2] + v[3];
    s[t] = lsum;
    __syncthreads();
    for (int o = 1; o < 512; o <<= 1) {
        int xv = (t >= o) ? s[t - o] : 0;
        __syncthreads();
        s[t] += xv;
        __syncthreads();
    }
    int run = s[t] - lsum;
#pragma unroll
    for (int j = 0; j < 4; ++j) {
        if (base + j < NBUCK) cnt[base + j] = run;
        run += v[j];
    }
    __syncthreads();
    for (int i = t; i < NBUCK; i += 512) {
        pos[i] = cnt[i];
        int fi = i * NPART + w;
        ofsG[i] = off[fi] + partials[fi >> 10];
    }
    __syncthreads();

    // --- C: rank + LDS scatter ---
#pragma unroll
    for (int ii = 0; ii < EPT; ++ii) {
        if (myb[ii] >= 0) {
            int ld = atomicAdd(&pos[myb[ii]], 1);
            eb2[ld] = myrec[ii];
            bkt2[ld] = (unsigned short)myb[ii];
        }
    }
    __syncthreads();

    // --- D: coalesced global write (runs) ---
    for (int i = t; i < CHUNK; i += 512) {
        int2 rec = eb2[i];
        int b = bkt2[i];
        int dest = ofsG[b] + (i - cnt[b]);
        bcolval[dest] = rec;
    }
}

// ---------------- Fused: bucket_to_csr (first) || gemm1 (MFMA, LDS-free) ----------------
__global__ __launch_bounds__(256) void fused_csr_gemm1(
    const int* __restrict__ off, const int* __restrict__ partials,
    const int2* __restrict__ bcolval, int* __restrict__ rowptr,
    int2* __restrict__ epack,
    const float* __restrict__ x, const unsigned short* __restrict__ W1t,
    unsigned short* __restrict__ outd) {
    __shared__ int cnt[BROWS];
    __shared__ int pos[BROWS];
    __shared__ int s[BROWS];
    __shared__ int2 eb[EBCAP];
    if (blockIdx.x < NBUCK) {
        // ---- bucket_to_csr ----
        const int b = blockIdx.x;
        const int t = threadIdx.x;
        const int fi = b * NPART;
        const int s0 = off[fi] + partials[fi >> 10];
        const int send = (b == NBUCK - 1)
                             ? NE
                             : off[fi + NPART] + partials[(fi + NPART) >> 10];
        const int n = send - s0;
        const bool fits = (n <= EBCAP);
        if (t < BROWS) cnt[t] = 0;
        __syncthreads();
        int2 myv[10];
        if (fits) {
#pragma unroll
            for (int ii = 0; ii < 10; ++ii) {
                int i = t + ii * 256;
                int2 v = make_int2(0, 0);
                if (i < n) {
                    v = bcolval[s0 + i];
                    atomicAdd(&cnt[((unsigned)v.x) >> 20], 1);
                }
                myv[ii] = v;
            }
        } else {
            for (int i = t; i < n; i += 256)
                atomicAdd(&cnt[((unsigned)bcolval[s0 + i].x) >> 20], 1);
        }
        __syncthreads();
        int myc = (t < BROWS) ? cnt[t] : 0;
        if (t < BROWS) s[t] = myc;
        __syncthreads();
        for (int o = 1; o < BROWS; o <<= 1) {
            int xv = (t >= o && t < BROWS) ? s[t - o] : 0;
            __syncthreads();
            if (t < BROWS) s[t] += xv;
            __syncthreads();
        }
        if (t < BROWS) {
            int excl = s[t] - myc;
            pos[t] = excl;  // bucket-relative
            int row = b * BROWS + t;
            if (row < NN) rowptr[row] = s0 + excl;
        }
        if (b == 0 && t == 0) rowptr[NN] = NE;
        __syncthreads();
        if (fits) {
#pragma unroll
            for (int ii = 0; ii < 10; ++ii) {
                int i = t + ii * 256;
                if (i < n) {
                    int2 v = myv[ii];
                    int p = atomicAdd(&pos[((unsigned)v.x) >> 20], 1);
                    eb[p] = make_int2(v.x & 0xFFFFF, v.y);
                }
            }
            __syncthreads();
            for (int i = t; i < n; i += 256) epack[s0 + i] = eb[i];
        } else {
            for (int i = t; i < n; i += 256) {
                int2 v = bcolval[s0 + i];
                int p = atomicAdd(&pos[((unsigned)v.x) >> 20], 1);
                epack[s0 + p] = make_int2(v.x & 0xFFFFF, v.y);
            }
        }
    } else {
        // ---- gemm1: support1(bf16) = x(f32) @ W1 ----
        const int tid = threadIdx.x;
        const int lane = tid & 63;
        const int w = tid >> 6;
        const int quad = lane >> 4;
        const int m = lane & 15;
        const int row0 = (blockIdx.x - NBUCK) * 128 + w * 32;

        int rA = row0 + m;
        int rB = row0 + 16 + m;
        rA = rA < NN ? rA : NN - 1;  // clamp loads; stores guarded
        rB = rB < NN ? rB : NN - 1;
        const float* pA = x + (size_t)rA * FIN + quad * 8;
        const float* pB = x + (size_t)rB * FIN + quad * 8;

        f32x4 acc[2][8];
#pragma unroll
        for (int i = 0; i < 2; ++i)
#pragma unroll
            for (int nt = 0; nt < 8; ++nt) acc[i][nt] = (f32x4){0.f, 0.f, 0.f, 0.f};

        float4 a0 = *(const float4*)pA;
        float4 a1 = *(const float4*)(pA + 4);
        float4 b0 = *(const float4*)pB;
        float4 b1 = *(const float4*)(pB + 4);

        for (int ks = 0; ks < 16; ++ks) {
            const int kn = (ks + 1) & 15;  // last-iter prefetch wraps (discarded)
            float4 na0 = *(const float4*)(pA + kn * 32);
            float4 na1 = *(const float4*)(pA + kn * 32 + 4);
            float4 nb0 = *(const float4*)(pB + kn * 32);
            float4 nb1 = *(const float4*)(pB + kn * 32 + 4);

            bf16x8 fA = pack8(a0, a1);
            bf16x8 fB = pack8(b0, b1);
            bf16x8 bb[8];
#pragma unroll
            for (int nt = 0; nt < 8; ++nt)
                bb[nt] = *(const bf16x8*)(W1t + ((size_t)((nt * 16 + ks) * 64 + lane)) * 8);
#pragma unroll
            for (int nt = 0; nt < 8; ++nt) {
                acc[0][nt] = __builtin_amdgcn_mfma_f32_16x16x32_bf16(fA, bb[nt], acc[0][nt], 0, 0, 0);
                acc[1][nt] = __builtin_amdgcn_mfma_f32_16x16x32_bf16(fB, bb[nt], acc[1][nt], 0, 0, 0);
            }
            a0 = na0; a1 = na1; b0 = nb0; b1 = nb1;
        }

#pragma unroll
        for (int i = 0; i < 2; ++i)
#pragma unroll
            for (int nt = 0; nt < 8; ++nt) {
                int col = nt * 16 + m;
#pragma unroll
                for (int r = 0; r < 4; ++r) {
                    int row = row0 + i * 16 + quad * 4 + r;
                    if (row < NN) outd[(size_t)row * FHID + col] = f2bf(acc[i][nt][r]);
                }
            }
    }
}

// ---------------- SpMM1 + bias + relu + GEMM2 (fused) ----------------
// Wave-per-row grid-stride. Descriptors at wave-uniform addresses -> SMEM
// scalar loads (zero VALU); gathers saddr-form (SGPR col); FMA val operand
// from SGPR. Matvec: readlane->SGPR pk, SALU extraction, W2 pre-paired in
// LDS (one ds_read_b64/jj); all lanes compute the full k-sum (cols
// duplicated across halves, no shfl); lanes<32 store.
__global__ __launch_bounds__(256) void spmm1_fused(const int* __restrict__ rowptr,
                                                   const int2* __restrict__ epack,
                                                   const unsigned short* __restrict__ dense,
                                                   const float* __restrict__ b1,
                                                   const float* __restrict__ W2,
                                                   unsigned short* __restrict__ support2) {
    __shared__ float2 w2p[64 * 32];  // (W2[2jj][c], W2[2jj+1][c]) : 16KB
    const int t = threadIdx.x;
    for (int i = t; i < 2048; i += 256) {
        int jj = i >> 5, c = i & 31;
        w2p[i] = make_float2(W2[(2 * jj) * FOUT + c], W2[(2 * jj + 1) * FOUT + c]);
    }
    __syncthreads();

    const int lane = t & 63;
    const int c31 = lane & 31;
    const unsigned* d32 = (const unsigned*)dense;
    const float2 bb = *(const float2*)(b1 + lane * 2);
    const int nwaves = gridDim.x * 4;

    for (int row = blockIdx.x * 4 + (t >> 6); row < NN; row += nwaves) {
        const int start = __builtin_amdgcn_readfirstlane(rowptr[row]);
        const int cnt = __builtin_amdgcn_readfirstlane(rowptr[row + 1]) - start;
        float acc0 = 0.f, acc1 = 0.f;

        int j = 0;
        for (; j + 16 <= cnt; j += 16) {
            int sc[16];
            float sv[16];
#pragma unroll
            for (int k = 0; k < 16; ++k) {  // uniform addr -> s_load
                int2 e = epack[start + j + k];
                sc[k] = e.x;
                sv[k] = __int_as_float(e.y);
            }
            unsigned d[16];
#pragma unroll
            for (int k = 0; k < 16; ++k)
                d[k] = d32[((size_t)sc[k] << 6) + lane];  // saddr gather
#pragma unroll
            for (int k = 0; k < 16; ++k) {
                acc0 = fmaf(sv[k], bflo(d[k]), acc0);
                acc1 = fmaf(sv[k], bfhi(d[k]), acc1);
            }
        }
        const int rem = cnt - j;
        if (rem > 0) {
            int sc[16];
            float sv[16];
#pragma unroll
            for (int k = 0; k < 16; ++k) {
                int idx = j + (k < rem ? k : rem - 1);  // scalar clamp
                int2 e = epack[start + idx];
                sc[k] = e.x;
                sv[k] = (k < rem) ? __int_as_float(e.y) : 0.f;  // scalar select
            }
            unsigned d[16];
#pragma unroll
            for (int k = 0; k < 16; ++k)
                d[k] = d32[((size_t)sc[k] << 6) + lane];
#pragma unroll
            for (int k = 0; k < 16; ++k) {
                acc0 = fmaf(sv[k], bflo(d[k]), acc0);
                acc1 = fmaf(sv[k], bfhi(d[k]), acc1);
            }
        }
        // bias + relu; pack lane's h chunk (cols 2*lane, 2*lane+1)
        float h0 = fmaxf(acc0 + bb.x, 0.f);
        float h1 = fmaxf(acc1 + bb.y, 0.f);
        unsigned packed = (unsigned)f2bf(h0) | ((unsigned)f2bf(h1) << 16);
        // fused gemm2: full k-sum per lane for col c31
        float p = 0.f;
#pragma unroll
        for (int jj = 0; jj < 64; ++jj) {
            unsigned pk = (unsigned)__builtin_amdgcn_readlane((int)packed, jj);
            float he = __uint_as_float(pk << 16);          // SALU
            float ho = __uint_as_float(pk & 0xffff0000u);  // SALU
            float2 w = w2p[jj * 32 + c31];                 // ds_read_b64
            p = fmaf(he, w.x, p);
            p = fmaf(ho, w.y, p);
        }
        if (lane < 32) support2[(size_t)row * FOUT + lane] = f2bf(p);
    }
}

// ------- SpMM2 + bias + log_softmax (fp32 out) -------
// Wave-per-row. Descriptors scalar-loaded; quad q takes edge 4g+q of each
// 4-edge group via a 2-level cndmask tree (SGPR sources); dword gathers.
__global__ __launch_bounds__(256) void spmm2_kernel(const int* __restrict__ rowptr,
                                                    const int2* __restrict__ epack,
                                                    const unsigned short* __restrict__ dense,
                                                    const float* __restrict__ b2,
                                                    float* __restrict__ out) {
    const int lane = threadIdx.x & 63;
    const int row = blockIdx.x * 4 + (threadIdx.x >> 6);
    const int start = __builtin_amdgcn_readfirstlane(rowptr[row]);
    const int cnt = __builtin_amdgcn_readfirstlane(rowptr[row + 1]) - start;
    const int quad = lane >> 4;
    const int sl16 = lane & 15;
    const bool qb0 = (quad & 1) != 0;
    const bool qb1 = (quad & 2) != 0;
    const unsigned* d32 = (const unsigned*)dense;
    float acc0 = 0.f, acc1 = 0.f;

    int j = 0;
    for (; j + 16 <= cnt; j += 16) {
#pragma unroll
        for (int g = 0; g < 4; ++g) {
            int2 e0 = epack[start + j + g * 4 + 0];  // uniform -> s_load
            int2 e1 = epack[start + j + g * 4 + 1];
            int2 e2 = epack[start + j + g * 4 + 2];
            int2 e3 = epack[start + j + g * 4 + 3];
            int cA = qb0 ? e1.x : e0.x;
            int cB = qb0 ? e3.x : e2.x;
            int cc = qb1 ? cB : cA;
            float vA = qb0 ? __int_as_float(e1.y) : __int_as_float(e0.y);
            float vB = qb0 ? __int_as_float(e3.y) : __int_as_float(e2.y);
            float vv = qb1 ? vB : vA;
            unsigned dv = d32[((size_t)cc << 4) + sl16];
            acc0 = fmaf(vv, bflo(dv), acc0);
            acc1 = fmaf(vv, bfhi(dv), acc1);
        }
    }
    const int rem = cnt - j;
    if (rem > 0) {
#pragma unroll
        for (int g = 0; g < 4; ++g) {
            if (g * 4 < rem) {  // uniform guard
                int i0 = j + min(g * 4 + 0, rem - 1);
                int i1 = j + min(g * 4 + 1, rem - 1);
                int i2 = j + min(g * 4 + 2, rem - 1);
                int i3 = j + min(g * 4 + 3, rem - 1);
                int2 e0 = epack[start + i0];
                int2 e1 = epack[start + i1];
                int2 e2 = epack[start + i2];
                int2 e3 = epack[start + i3];
                float f0 = (g * 4 + 0 < rem) ? __int_as_float(e0.y) : 0.f;
                float f1 = (g * 4 + 1 < rem) ? __int_as_float(e1.y) : 0.f;
                float f2 = (g * 4 + 2 < rem) ? __int_as_float(e2.y) : 0.f;
                float f3 = (g * 4 + 3 < rem) ? __int_as_float(e3.y) : 0.f;
                int cA = qb0 ? e1.x : e0.x;
                int cB = qb0 ? e3.x : e2.x;
                int cc = qb1 ? cB : cA;
                float vA = qb0 ? f1 : f0;
                float vB = qb0 ? f3 : f2;
                float vv = qb1 ? vB : vA;
                unsigned dv = d32[((size_t)cc << 4) + sl16];
                acc0 = fmaf(vv, bflo(dv), acc0);
                acc1 = fmaf(vv, bfhi(dv), acc1);
            }
        }
    }
    // combine quad partials: all lanes end with totals for cols 2*sl16(+1)
    acc0 += __shfl_xor(acc0, 16, 64);
    acc0 += __shfl_xor(acc0, 32, 64);
    acc1 += __shfl_xor(acc1, 16, 64);
    acc1 += __shfl_xor(acc1, 32, 64);
    float2 bb = *(const float2*)(b2 + sl16 * 2);
    acc0 += bb.x;
    acc1 += bb.y;
    float m = fmaxf(acc0, acc1);
#pragma unroll
    for (int mask = 8; mask >= 1; mask >>= 1) m = fmaxf(m, __shfl_xor(m, mask, 64));
    float ssum = expf(acc0 - m) + expf(acc1 - m);
#pragma unroll
    for (int mask = 8; mask >= 1; mask >>= 1) ssum += __shfl_xor(ssum, mask, 64);
    float lse = m + logf(ssum);
    if (lane < 16) {
        float2 st = make_float2(acc0 - lse, acc1 - lse);
        *(float2*)(out + (size_t)row * FOUT + sl16 * 2) = st;
    }
}

extern "C" void kernel_launch(void* const* d_in, const int* in_sizes, int n_in,
                              void* d_out, int out_size, void* d_ws, size_t ws_size,
                              hipStream_t stream) {
    const float* x = (const float*)d_in[0];
    const int* erow = (const int*)d_in[1];
    const int* ecol = (const int*)d_in[2];
    const float* eval = (const float*)d_in[3];
    const float* W1 = (const float*)d_in[4];
    const float* b1 = (const float*)d_in[5];
    const float* W2 = (const float*)d_in[6];
    const float* b2 = (const float*)d_in[7];
    float* out = (float*)d_out;

    char* ws = (char*)d_ws;
    size_t off_b = 0;
    auto walloc = [&](size_t bytes) -> void* {
        void* p = ws + off_b;
        off_b = (off_b + bytes + 255) & ~(size_t)255;
        return p;
    };
    int2* epack = (int2*)walloc((size_t)NE * 8);
    int* rowptr = (int*)walloc((size_t)(NN + 1) * 4);
    int* cntG = (int*)walloc((size_t)TOT * 4);
    int* off = (int*)walloc((size_t)TOT * 4);
    int* partials = (int*)walloc(4096);
    unsigned short* W1t = (unsigned short*)walloc((size_t)FHID * FIN * 2);
    int2* bcolval = (int2*)walloc((size_t)NE * 8);
    unsigned short* support1 = (unsigned short*)walloc((size_t)NN * FHID * 2);
    unsigned short* support2 = (unsigned short*)walloc((size_t)NN * FOUT * 2);

    fused_prep_hist<<<NPART + 256, 256, 0, stream>>>(W1, W1t, erow, cntG);
    scan1_kernel<<<NSCAN1, 256, 0, stream>>>(cntG, off, partials);
    scan2_kernel<<<1, 512, 0, stream>>>(partials);
    scatter_part<<<NPART, 512, 0, stream>>>(erow, ecol, eval, off, partials, bcolval);
    fused_csr_gemm1<<<NBUCK + GG1, 256, 0, stream>>>(off, partials, bcolval, rowptr,
                                                     epack, x, W1t, support1);
    spmm1_fused<<<2048, 256, 0, stream>>>(rowptr, epack, support1, b1, W2, support2);
    spmm2_kernel<<<NN / 4, 256, 0, stream>>>(rowptr, epack, support2, b2, out);
}